// Round 1
// baseline (2991.125 us; speedup 1.0000x reference)
//
#include <hip/hip_runtime.h>
#include <math.h>

// Problem constants
#define BB 4
#define SS 256
#define EE 512
#define HH 8
#define HD 64
#define FF 2048
#define LL 4
#define VV 32000
#define BS (BB*SS)          // 1024 tokens
#define SQRT_E 22.627416997969522f
#define ATTN_SCALE 0.125f   // 1/sqrt(64)

// ---------------- LayerNorm over E=512, one block (256 thr) per row ----------------
__global__ void ln_kernel(const float* __restrict__ in, const float* __restrict__ sc,
                          const float* __restrict__ bi, float* __restrict__ out) {
    int row = blockIdx.x;
    int t = threadIdx.x;
    const float* r = in + (size_t)row * EE;
    float v0 = r[t], v1 = r[t + 256];
    float sum = v0 + v1, sq = v0 * v0 + v1 * v1;
    #pragma unroll
    for (int off = 32; off; off >>= 1) {
        sum += __shfl_xor(sum, off);
        sq  += __shfl_xor(sq, off);
    }
    __shared__ float ssum[4], ssq[4];
    int wid = t >> 6, lane = t & 63;
    if (lane == 0) { ssum[wid] = sum; ssq[wid] = sq; }
    __syncthreads();
    sum = ssum[0] + ssum[1] + ssum[2] + ssum[3];
    sq  = ssq[0] + ssq[1] + ssq[2] + ssq[3];
    float mean = sum * (1.0f / EE);
    float var  = sq * (1.0f / EE) - mean * mean;
    float rstd = rsqrtf(var + 1e-5f);
    out[(size_t)row * EE + t]       = (v0 - mean) * rstd * sc[t] + bi[t];
    out[(size_t)row * EE + t + 256] = (v1 - mean) * rstd * sc[t + 256] + bi[t + 256];
}

// ---------------- Embedding gather * sqrt(E) + LayerNorm ----------------
__global__ void embed_ln_kernel(const int* __restrict__ src, const float* __restrict__ emb,
                                const float* __restrict__ sc, const float* __restrict__ bi,
                                float* __restrict__ out) {
    int row = blockIdx.x;          // token index
    int t = threadIdx.x;
    const float* r = emb + (size_t)src[row] * EE;
    float v0 = r[t] * SQRT_E, v1 = r[t + 256] * SQRT_E;
    float sum = v0 + v1, sq = v0 * v0 + v1 * v1;
    #pragma unroll
    for (int off = 32; off; off >>= 1) {
        sum += __shfl_xor(sum, off);
        sq  += __shfl_xor(sq, off);
    }
    __shared__ float ssum[4], ssq[4];
    int wid = t >> 6, lane = t & 63;
    if (lane == 0) { ssum[wid] = sum; ssq[wid] = sq; }
    __syncthreads();
    sum = ssum[0] + ssum[1] + ssum[2] + ssum[3];
    sq  = ssq[0] + ssq[1] + ssq[2] + ssq[3];
    float mean = sum * (1.0f / EE);
    float var  = sq * (1.0f / EE) - mean * mean;
    float rstd = rsqrtf(var + 1e-5f);
    out[(size_t)row * EE + t]       = (v0 - mean) * rstd * sc[t] + bi[t];
    out[(size_t)row * EE + t + 256] = (v1 - mean) * rstd * sc[t + 256] + bi[t + 256];
}

// ---------------- Tiled NT GEMM: C[M,N] = A[M,K] @ W[N,K]^T (+bias, epilogue) ----------------
// MODE 0: C = acc + bias
// MODE 1: C = gelu_exact(acc + bias)
// MODE 2: C = res + acc + bias   (residual add; res may alias C)
template <int MODE>
__global__ void gemm_nt(const float* __restrict__ A, const float* __restrict__ W,
                        const float* __restrict__ bias, float* __restrict__ C,
                        const float* __restrict__ res, int M, int N, int K) {
    __shared__ float As[64][17];
    __shared__ float Ws[64][17];
    int tid = threadIdx.x;
    int tx = tid & 15, ty = tid >> 4;
    int bm = blockIdx.y * 64, bn = blockIdx.x * 64;
    float acc[4][4] = {};
    for (int k0 = 0; k0 < K; k0 += 16) {
        #pragma unroll
        for (int i = 0; i < 4; i++) {
            int idx = tid + i * 256;
            int r = idx >> 4, c = idx & 15;
            As[r][c] = A[(size_t)(bm + r) * K + k0 + c];
            Ws[r][c] = W[(size_t)(bn + r) * K + k0 + c];
        }
        __syncthreads();
        #pragma unroll
        for (int kk = 0; kk < 16; kk++) {
            float a[4], w[4];
            #pragma unroll
            for (int i = 0; i < 4; i++) a[i] = As[ty * 4 + i][kk];
            #pragma unroll
            for (int j = 0; j < 4; j++) w[j] = Ws[tx * 4 + j][kk];
            #pragma unroll
            for (int i = 0; i < 4; i++)
                #pragma unroll
                for (int j = 0; j < 4; j++)
                    acc[i][j] += a[i] * w[j];
        }
        __syncthreads();
    }
    #pragma unroll
    for (int i = 0; i < 4; i++) {
        int row = bm + ty * 4 + i;
        #pragma unroll
        for (int j = 0; j < 4; j++) {
            int col = bn + tx * 4 + j;
            float v = acc[i][j] + bias[col];
            if (MODE == 1) v = 0.5f * v * (1.0f + erff(v * 0.7071067811865476f));
            if (MODE == 2) v += res[(size_t)row * N + col];
            C[(size_t)row * N + col] = v;
        }
    }
}

// ---------------- Attention: one block per (b, h, query l), 256 threads ----------------
// scores[m] = scale * q.k[m] + q.rel[(m-l)+S-1, h] + (m>l ? 1.0 : 0.0)  -- note: bool mask
// added as float (+1.0), matching the torch/jax reference exactly.
__global__ void attn_kernel(const float* __restrict__ qkv, const float* __restrict__ rel_table,
                            float* __restrict__ o) {
    int blk = blockIdx.x;
    int l = blk & (SS - 1);
    int bh = blk >> 8;
    int h = bh & (HH - 1);
    int b = bh >> 3;
    int t = threadIdx.x;
    int wid = t >> 6, lane = t & 63;

    __shared__ float qs[HD];
    __shared__ float attn_s[SS];
    __shared__ float swave[4];
    __shared__ float opart[4][HD];

    const float* qrow = qkv + (size_t)(b * SS + l) * (3 * EE) + h * HD;
    if (t < HD) qs[t] = qrow[t];
    __syncthreads();

    // score for key index m = t
    const float* krow   = qkv + (size_t)(b * SS + t) * (3 * EE) + EE + h * HD;
    const float* relrow = rel_table + (size_t)(t - l + SS - 1) * EE + h * HD;
    const float4* k4 = reinterpret_cast<const float4*>(krow);
    const float4* r4 = reinterpret_cast<const float4*>(relrow);
    float s1 = 0.f, s2 = 0.f;
    #pragma unroll
    for (int d4 = 0; d4 < HD / 4; d4++) {
        float4 kv = k4[d4], rv = r4[d4];
        float q0 = qs[4 * d4], q1 = qs[4 * d4 + 1], q2 = qs[4 * d4 + 2], q3 = qs[4 * d4 + 3];
        s1 += q0 * kv.x + q1 * kv.y + q2 * kv.z + q3 * kv.w;
        s2 += q0 * rv.x + q1 * rv.y + q2 * rv.z + q3 * rv.w;
    }
    float val = s1 * ATTN_SCALE + s2 + ((t > l) ? 1.0f : 0.0f);

    // block max
    float m = val;
    #pragma unroll
    for (int off = 32; off; off >>= 1) m = fmaxf(m, __shfl_xor(m, off));
    if (lane == 0) swave[wid] = m;
    __syncthreads();
    m = fmaxf(fmaxf(swave[0], swave[1]), fmaxf(swave[2], swave[3]));
    float p = expf(val - m);
    // block sum
    float s = p;
    #pragma unroll
    for (int off = 32; off; off >>= 1) s += __shfl_xor(s, off);
    __syncthreads();
    if (lane == 0) swave[wid] = s;
    __syncthreads();
    float tot = swave[0] + swave[1] + swave[2] + swave[3];
    attn_s[t] = p;
    __syncthreads();

    // o[d] = sum_m attn[m] * v[b,m,h,d] / tot ; 4 partials of 64 keys each
    int d = t & 63, part = t >> 6;
    const float* vbase = qkv + (size_t)(b * SS) * (3 * EE) + 2 * EE + h * HD + d;
    float acc = 0.f;
    int m0 = part * 64;
    #pragma unroll 8
    for (int mm = m0; mm < m0 + 64; mm++)
        acc += attn_s[mm] * vbase[(size_t)mm * (3 * EE)];
    opart[part][d] = acc;
    __syncthreads();
    if (t < 64) {
        float ov = (opart[0][d] + opart[1][d] + opart[2][d] + opart[3][d]) / tot;
        o[(size_t)(b * SS + l) * EE + h * HD + d] = ov;
    }
}

extern "C" void kernel_launch(void* const* d_in, const int* in_sizes, int n_in,
                              void* d_out, int out_size, void* d_ws, size_t ws_size,
                              hipStream_t stream) {
    const int*   src    = (const int*)  d_in[0];
    const float* emb    = (const float*)d_in[1];
    const float* rel    = (const float*)d_in[2];
    const float* nin_s  = (const float*)d_in[3];
    const float* nin_b  = (const float*)d_in[4];
    const float* inW    = (const float*)d_in[5];
    const float* inB    = (const float*)d_in[6];
    const float* outW   = (const float*)d_in[7];
    const float* outB   = (const float*)d_in[8];
    const float* ln1_s  = (const float*)d_in[9];
    const float* ln1_b  = (const float*)d_in[10];
    const float* ln2_s  = (const float*)d_in[11];
    const float* ln2_b  = (const float*)d_in[12];
    const float* w1     = (const float*)d_in[13];
    const float* b1     = (const float*)d_in[14];
    const float* w2     = (const float*)d_in[15];
    const float* b2     = (const float*)d_in[16];
    const float* normf_s= (const float*)d_in[17];
    const float* normf_b= (const float*)d_in[18];
    const float* dec_w  = (const float*)d_in[19];
    const float* dec_b  = (const float*)d_in[20];

    float* x     = (float*)d_ws;                 // [1024, 512]
    float* h     = x + (size_t)BS * EE;          // [1024, 512]
    float* qkv   = h + (size_t)BS * EE;          // [1024, 1536]
    float* o     = qkv + (size_t)BS * 3 * EE;    // [1024, 512]
    float* ffmid = o + (size_t)BS * EE;          // [1024, 2048]
    float* out   = (float*)d_out;                // [1024, 32000]

    embed_ln_kernel<<<BS, 256, 0, stream>>>(src, emb, nin_s, nin_b, x);

    for (int l = 0; l < LL; l++) {
        ln_kernel<<<BS, 256, 0, stream>>>(x, ln1_s + l * EE, ln1_b + l * EE, h);
        gemm_nt<0><<<dim3(3 * EE / 64, BS / 64), 256, 0, stream>>>(
            h, inW + (size_t)l * 3 * EE * EE, inB + (size_t)l * 3 * EE, qkv, nullptr,
            BS, 3 * EE, EE);
        attn_kernel<<<BB * HH * SS, 256, 0, stream>>>(qkv, rel, o);
        gemm_nt<2><<<dim3(EE / 64, BS / 64), 256, 0, stream>>>(
            o, outW + (size_t)l * EE * EE, outB + (size_t)l * EE, x, x,
            BS, EE, EE);
        ln_kernel<<<BS, 256, 0, stream>>>(x, ln2_s + l * EE, ln2_b + l * EE, h);
        gemm_nt<1><<<dim3(FF / 64, BS / 64), 256, 0, stream>>>(
            h, w1 + (size_t)l * FF * EE, b1 + (size_t)l * FF, ffmid, nullptr,
            BS, FF, EE);
        gemm_nt<2><<<dim3(EE / 64, BS / 64), 256, 0, stream>>>(
            ffmid, w2 + (size_t)l * EE * FF, b2 + (size_t)l * EE, x, x,
            BS, EE, FF);
    }

    ln_kernel<<<BS, 256, 0, stream>>>(x, normf_s, normf_b, h);
    gemm_nt<0><<<dim3(VV / 64, BS / 64), 256, 0, stream>>>(
        h, dec_w, dec_b, out, nullptr, BS, VV, EE);
}

// Round 2
// 1404.345 us; speedup vs baseline: 2.1299x; 2.1299x over previous
//
#include <hip/hip_runtime.h>
#include <hip/hip_bf16.h>
#include <math.h>

// Problem constants
#define BB 4
#define SS 256
#define EE 512
#define HH 8
#define HD 64
#define FFD 2048
#define LL 4
#define VV 32000
#define BS (BB*SS)          // 1024 tokens
#define SQRT_E 22.627416997969522f
#define ATTN_SCALE 0.125f   // 1/sqrt(64)

typedef __bf16 bf16;
typedef __attribute__((ext_vector_type(4))) __bf16 bf16x4;
typedef __attribute__((ext_vector_type(8))) __bf16 bf16x8;
typedef __attribute__((ext_vector_type(4))) float f32x4;

#define GLOBAL_AS __attribute__((address_space(1)))
#define LDS_AS    __attribute__((address_space(3)))

__device__ __forceinline__ void load_lds16(const bf16* g, bf16* l) {
    // async global->LDS, 16 bytes/lane. LDS dest must be wave-uniform base + lane*16.
    __builtin_amdgcn_global_load_lds((const GLOBAL_AS unsigned int*)g,
                                     (LDS_AS unsigned int*)l, 16, 0, 0);
}

// ---------------- fp32 -> bf16 conversion (RNE), float4 vectorized ----------------
__global__ void cvt_bf16(const float* __restrict__ in, bf16* __restrict__ out, int n) {
    int i = (blockIdx.x * 256 + threadIdx.x) * 4;
    if (i < n) {
        float4 v = *(const float4*)(in + i);
        bf16x4 o;
        o[0] = (bf16)v.x; o[1] = (bf16)v.y; o[2] = (bf16)v.z; o[3] = (bf16)v.w;
        *(bf16x4*)(out + i) = o;
    }
}

// ---------------- LayerNorm over E=512, one block (256 thr) per row ----------------
template <typename OT>
__global__ void ln_kernel(const float* __restrict__ in, const float* __restrict__ sc,
                          const float* __restrict__ bi, OT* __restrict__ out) {
    int row = blockIdx.x;
    int t = threadIdx.x;
    const float* r = in + (size_t)row * EE;
    float v0 = r[t], v1 = r[t + 256];
    float sum = v0 + v1, sq = v0 * v0 + v1 * v1;
    #pragma unroll
    for (int off = 32; off; off >>= 1) {
        sum += __shfl_xor(sum, off);
        sq  += __shfl_xor(sq, off);
    }
    __shared__ float ssum[4], ssq[4];
    int wid = t >> 6, lane = t & 63;
    if (lane == 0) { ssum[wid] = sum; ssq[wid] = sq; }
    __syncthreads();
    sum = ssum[0] + ssum[1] + ssum[2] + ssum[3];
    sq  = ssq[0] + ssq[1] + ssq[2] + ssq[3];
    float mean = sum * (1.0f / EE);
    float var  = sq * (1.0f / EE) - mean * mean;
    float rstd = rsqrtf(var + 1e-5f);
    out[(size_t)row * EE + t]       = (OT)((v0 - mean) * rstd * sc[t] + bi[t]);
    out[(size_t)row * EE + t + 256] = (OT)((v1 - mean) * rstd * sc[t + 256] + bi[t + 256]);
}

// ---------------- Embedding gather * sqrt(E) + LayerNorm (fp32 out, residual stream) ----
__global__ void embed_ln_kernel(const int* __restrict__ src, const float* __restrict__ emb,
                                const float* __restrict__ sc, const float* __restrict__ bi,
                                float* __restrict__ out) {
    int row = blockIdx.x;
    int t = threadIdx.x;
    const float* r = emb + (size_t)src[row] * EE;
    float v0 = r[t] * SQRT_E, v1 = r[t + 256] * SQRT_E;
    float sum = v0 + v1, sq = v0 * v0 + v1 * v1;
    #pragma unroll
    for (int off = 32; off; off >>= 1) {
        sum += __shfl_xor(sum, off);
        sq  += __shfl_xor(sq, off);
    }
    __shared__ float ssum[4], ssq[4];
    int wid = t >> 6, lane = t & 63;
    if (lane == 0) { ssum[wid] = sum; ssq[wid] = sq; }
    __syncthreads();
    sum = ssum[0] + ssum[1] + ssum[2] + ssum[3];
    sq  = ssq[0] + ssq[1] + ssq[2] + ssq[3];
    float mean = sum * (1.0f / EE);
    float var  = sq * (1.0f / EE) - mean * mean;
    float rstd = rsqrtf(var + 1e-5f);
    out[(size_t)row * EE + t]       = (v0 - mean) * rstd * sc[t] + bi[t];
    out[(size_t)row * EE + t + 256] = (v1 - mean) * rstd * sc[t + 256] + bi[t + 256];
}

// ---------------- bf16 MFMA NT GEMM: C[M,N] = A[M,K] @ W[N,K]^T ----------------
// 256 threads = 4 waves in 2x2; each wave computes (BM/2)x(BN/2) via FMxFN 16x16 MFMAs.
// BK = 32 (one 16x16x32 MFMA per frag-pair per K-step).
// MODE 0: +bias ; MODE 1: gelu_exact(+bias) ; MODE 2: res + (+bias)
// OBF16: store bf16 instead of fp32.
template <int BM, int BN, int MODE, int OBF16>
__global__ __launch_bounds__(256) void gemm_bf16(
        const bf16* __restrict__ A, const bf16* __restrict__ W,
        const float* __restrict__ bias, void* __restrict__ Cout,
        const float* __restrict__ res, int M, int N, int K) {
    constexpr int FM = BM / 32, FN = BN / 32;
    __shared__ bf16 Atile[BM * 32];
    __shared__ bf16 Btile[BN * 32];
    int tid = threadIdx.x;
    int wid = tid >> 6, lane = tid & 63;
    int wm = (wid >> 1) * (BM / 2), wn = (wid & 1) * (BN / 2);
    int bm = blockIdx.x * BM, bn = blockIdx.y * BN;

    f32x4 acc[FM][FN];
    #pragma unroll
    for (int i = 0; i < FM; i++)
        #pragma unroll
        for (int j = 0; j < FN; j++)
            acc[i][j] = (f32x4){0.f, 0.f, 0.f, 0.f};

    int mrow = lane & 15, kq = (lane >> 4) * 8;

    for (int k0 = 0; k0 < K; k0 += 32) {
        // stage A tile: BM rows x 32 k, 64 B/row, 16 B per lane per issue
        #pragma unroll
        for (int it = 0; it < BM / 64; it++) {
            int c = it * 256 + tid;
            int row = c >> 2, kc = (c & 3) * 8;
            load_lds16(A + (size_t)(bm + row) * K + k0 + kc, Atile + c * 8);
        }
        #pragma unroll
        for (int it = 0; it < BN / 64; it++) {
            int c = it * 256 + tid;
            int row = c >> 2, kc = (c & 3) * 8;
            load_lds16(W + (size_t)(bn + row) * K + k0 + kc, Btile + c * 8);
        }
        __syncthreads();

        bf16x8 af[FM], bfv[FN];
        #pragma unroll
        for (int i = 0; i < FM; i++)
            af[i] = *(const bf16x8*)(Atile + (wm + i * 16 + mrow) * 32 + kq);
        #pragma unroll
        for (int j = 0; j < FN; j++)
            bfv[j] = *(const bf16x8*)(Btile + (wn + j * 16 + mrow) * 32 + kq);
        #pragma unroll
        for (int i = 0; i < FM; i++)
            #pragma unroll
            for (int j = 0; j < FN; j++)
                acc[i][j] = __builtin_amdgcn_mfma_f32_16x16x32_bf16(af[i], bfv[j], acc[i][j], 0, 0, 0);
        __syncthreads();
    }

    // epilogue: C/D layout col = lane&15, row = (lane>>4)*4 + reg
    #pragma unroll
    for (int i = 0; i < FM; i++) {
        int row0 = bm + wm + i * 16 + (lane >> 4) * 4;
        #pragma unroll
        for (int j = 0; j < FN; j++) {
            int col = bn + wn + j * 16 + (lane & 15);
            float bv = bias[col];
            #pragma unroll
            for (int r = 0; r < 4; r++) {
                int row = row0 + r;
                float v = acc[i][j][r] + bv;
                if (MODE == 1) v = 0.5f * v * (1.0f + erff(v * 0.7071067811865476f));
                if (MODE == 2) v += res[(size_t)row * N + col];
                if (OBF16) ((bf16*)Cout)[(size_t)row * N + col] = (bf16)v;
                else       ((float*)Cout)[(size_t)row * N + col] = v;
            }
        }
    }
}

// ---------------- fp32 fallback GEMM (round-1) ----------------
template <int MODE>
__global__ void gemm_nt(const float* __restrict__ A, const float* __restrict__ W,
                        const float* __restrict__ bias, float* __restrict__ C,
                        const float* __restrict__ res, int M, int N, int K) {
    __shared__ float As[64][17];
    __shared__ float Ws[64][17];
    int tid = threadIdx.x;
    int tx = tid & 15, ty = tid >> 4;
    int bm = blockIdx.y * 64, bn = blockIdx.x * 64;
    float acc[4][4] = {};
    for (int k0 = 0; k0 < K; k0 += 16) {
        #pragma unroll
        for (int i = 0; i < 4; i++) {
            int idx = tid + i * 256;
            int r = idx >> 4, c = idx & 15;
            As[r][c] = A[(size_t)(bm + r) * K + k0 + c];
            Ws[r][c] = W[(size_t)(bn + r) * K + k0 + c];
        }
        __syncthreads();
        #pragma unroll
        for (int kk = 0; kk < 16; kk++) {
            float a[4], w[4];
            #pragma unroll
            for (int i = 0; i < 4; i++) a[i] = As[ty * 4 + i][kk];
            #pragma unroll
            for (int j = 0; j < 4; j++) w[j] = Ws[tx * 4 + j][kk];
            #pragma unroll
            for (int i = 0; i < 4; i++)
                #pragma unroll
                for (int j = 0; j < 4; j++)
                    acc[i][j] += a[i] * w[j];
        }
        __syncthreads();
    }
    #pragma unroll
    for (int i = 0; i < 4; i++) {
        int row = bm + ty * 4 + i;
        #pragma unroll
        for (int j = 0; j < 4; j++) {
            int col = bn + tx * 4 + j;
            float v = acc[i][j] + bias[col];
            if (MODE == 1) v = 0.5f * v * (1.0f + erff(v * 0.7071067811865476f));
            if (MODE == 2) v += res[(size_t)row * N + col];
            C[(size_t)row * N + col] = v;
        }
    }
}

// ---------------- Attention: one block per (b, h, query l), 256 threads ----------------
// scores[m] = scale*q.k[m] + q.rel[(m-l)+S-1, h] + (m>l ? 1.0 : 0.0) (bool mask added as float)
template <typename OT>
__global__ void attn_kernel(const float* __restrict__ qkv, const float* __restrict__ rel_table,
                            OT* __restrict__ o) {
    int blk = blockIdx.x;
    int l = blk & (SS - 1);
    int bh = blk >> 8;
    int h = bh & (HH - 1);
    int b = bh >> 3;
    int t = threadIdx.x;
    int wid = t >> 6, lane = t & 63;

    __shared__ float qs[HD];
    __shared__ float attn_s[SS];
    __shared__ float swave[4];
    __shared__ float opart[4][HD];

    const float* qrow = qkv + (size_t)(b * SS + l) * (3 * EE) + h * HD;
    if (t < HD) qs[t] = qrow[t];
    __syncthreads();

    const float* krow   = qkv + (size_t)(b * SS + t) * (3 * EE) + EE + h * HD;
    const float* relrow = rel_table + (size_t)(t - l + SS - 1) * EE + h * HD;
    const float4* k4 = reinterpret_cast<const float4*>(krow);
    const float4* r4 = reinterpret_cast<const float4*>(relrow);
    float s1 = 0.f, s2 = 0.f;
    #pragma unroll
    for (int d4 = 0; d4 < HD / 4; d4++) {
        float4 kv = k4[d4], rv = r4[d4];
        float q0 = qs[4 * d4], q1 = qs[4 * d4 + 1], q2 = qs[4 * d4 + 2], q3 = qs[4 * d4 + 3];
        s1 += q0 * kv.x + q1 * kv.y + q2 * kv.z + q3 * kv.w;
        s2 += q0 * rv.x + q1 * rv.y + q2 * rv.z + q3 * rv.w;
    }
    float val = s1 * ATTN_SCALE + s2 + ((t > l) ? 1.0f : 0.0f);

    float m = val;
    #pragma unroll
    for (int off = 32; off; off >>= 1) m = fmaxf(m, __shfl_xor(m, off));
    if (lane == 0) swave[wid] = m;
    __syncthreads();
    m = fmaxf(fmaxf(swave[0], swave[1]), fmaxf(swave[2], swave[3]));
    float p = expf(val - m);
    float s = p;
    #pragma unroll
    for (int off = 32; off; off >>= 1) s += __shfl_xor(s, off);
    __syncthreads();
    if (lane == 0) swave[wid] = s;
    __syncthreads();
    float tot = swave[0] + swave[1] + swave[2] + swave[3];
    attn_s[t] = p;
    __syncthreads();

    int d = t & 63, part = t >> 6;
    const float* vbase = qkv + (size_t)(b * SS) * (3 * EE) + 2 * EE + h * HD + d;
    float acc = 0.f;
    int m0 = part * 64;
    #pragma unroll 8
    for (int mm = m0; mm < m0 + 64; mm++)
        acc += attn_s[mm] * vbase[(size_t)mm * (3 * EE)];
    opart[part][d] = acc;
    __syncthreads();
    if (t < 64) {
        float ov = (opart[0][d] + opart[1][d] + opart[2][d] + opart[3][d]) / tot;
        o[(size_t)(b * SS + l) * EE + h * HD + d] = (OT)ov;
    }
}

extern "C" void kernel_launch(void* const* d_in, const int* in_sizes, int n_in,
                              void* d_out, int out_size, void* d_ws, size_t ws_size,
                              hipStream_t stream) {
    const int*   src    = (const int*)  d_in[0];
    const float* emb    = (const float*)d_in[1];
    const float* rel    = (const float*)d_in[2];
    const float* nin_s  = (const float*)d_in[3];
    const float* nin_b  = (const float*)d_in[4];
    const float* inW    = (const float*)d_in[5];
    const float* inB    = (const float*)d_in[6];
    const float* outW   = (const float*)d_in[7];
    const float* outB   = (const float*)d_in[8];
    const float* ln1_s  = (const float*)d_in[9];
    const float* ln1_b  = (const float*)d_in[10];
    const float* ln2_s  = (const float*)d_in[11];
    const float* ln2_b  = (const float*)d_in[12];
    const float* w1     = (const float*)d_in[13];
    const float* b1     = (const float*)d_in[14];
    const float* w2     = (const float*)d_in[15];
    const float* b2     = (const float*)d_in[16];
    const float* normf_s= (const float*)d_in[17];
    const float* normf_b= (const float*)d_in[18];
    const float* dec_w  = (const float*)d_in[19];
    const float* dec_b  = (const float*)d_in[20];
    float* out = (float*)d_out;   // [1024, 32000]

    // ---- workspace layout (fast bf16 path) ----
    const size_t n_inW  = (size_t)LL * 3 * EE * EE;   // 3,145,728
    const size_t n_outW = (size_t)LL * EE * EE;       // 1,048,576
    const size_t n_w1   = (size_t)LL * FFD * EE;      // 4,194,304
    const size_t n_w2   = (size_t)LL * EE * FFD;      // 4,194,304
    const size_t n_dec  = (size_t)VV * EE;            // 16,384,000

    float* x   = (float*)d_ws;                        // [BS,EE] fp32 residual stream
    float* qkv = x + (size_t)BS * EE;                 // [BS,3EE] fp32
    bf16*  hb  = (bf16*)(qkv + (size_t)BS * 3 * EE);  // [BS,EE]
    bf16*  ob  = hb + (size_t)BS * EE;                // [BS,EE]
    bf16*  ffb = ob + (size_t)BS * EE;                // [BS,FFD]
    bf16*  inWb  = ffb + (size_t)BS * FFD;
    bf16*  outWb = inWb + n_inW;
    bf16*  w1b   = outWb + n_outW;
    bf16*  w2b   = w1b + n_w1;
    bf16*  decWb = w2b + n_w2;
    size_t needed = (size_t)((char*)(decWb + n_dec) - (char*)d_ws);

    if (ws_size >= needed) {
        // ---- fast path: bf16 MFMA GEMMs ----
        cvt_bf16<<<(int)(n_inW  / 1024), 256, 0, stream>>>(inW,   inWb,  (int)n_inW);
        cvt_bf16<<<(int)(n_outW / 1024), 256, 0, stream>>>(outW,  outWb, (int)n_outW);
        cvt_bf16<<<(int)(n_w1   / 1024), 256, 0, stream>>>(w1,    w1b,   (int)n_w1);
        cvt_bf16<<<(int)(n_w2   / 1024), 256, 0, stream>>>(w2,    w2b,   (int)n_w2);
        cvt_bf16<<<(int)(n_dec  / 1024), 256, 0, stream>>>(dec_w, decWb, (int)n_dec);

        embed_ln_kernel<<<BS, 256, 0, stream>>>(src, emb, nin_s, nin_b, x);

        for (int l = 0; l < LL; l++) {
            ln_kernel<bf16><<<BS, 256, 0, stream>>>(x, ln1_s + l * EE, ln1_b + l * EE, hb);
            gemm_bf16<64, 64, 0, 0><<<dim3(BS / 64, 3 * EE / 64), 256, 0, stream>>>(
                hb, inWb + (size_t)l * 3 * EE * EE, inB + (size_t)l * 3 * EE, qkv, nullptr,
                BS, 3 * EE, EE);
            attn_kernel<bf16><<<BB * HH * SS, 256, 0, stream>>>(qkv, rel, ob);
            gemm_bf16<64, 64, 2, 0><<<dim3(BS / 64, EE / 64), 256, 0, stream>>>(
                ob, outWb + (size_t)l * EE * EE, outB + (size_t)l * EE, x, x,
                BS, EE, EE);
            ln_kernel<bf16><<<BS, 256, 0, stream>>>(x, ln2_s + l * EE, ln2_b + l * EE, hb);
            gemm_bf16<64, 64, 1, 1><<<dim3(BS / 64, FFD / 64), 256, 0, stream>>>(
                hb, w1b + (size_t)l * FFD * EE, b1 + (size_t)l * FFD, ffb, nullptr,
                BS, FFD, EE);
            gemm_bf16<64, 64, 2, 0><<<dim3(BS / 64, EE / 64), 256, 0, stream>>>(
                ffb, w2b + (size_t)l * EE * FFD, b2 + (size_t)l * EE, x, x,
                BS, EE, FFD);
        }

        ln_kernel<bf16><<<BS, 256, 0, stream>>>(x, normf_s, normf_b, hb);
        // decoder: blockIdx.x = M-tile so co-resident blocks share W tiles via L2
        gemm_bf16<128, 128, 0, 0><<<dim3(BS / 128, VV / 128), 256, 0, stream>>>(
            hb, decWb, dec_b, out, nullptr, BS, VV, EE);
    } else {
        // ---- fallback: round-1 fp32 path (needs ~20 MB ws) ----
        float* h     = x + (size_t)BS * EE;
        float* qkvf  = h + (size_t)BS * EE;
        float* o     = qkvf + (size_t)BS * 3 * EE;
        float* ffmid = o + (size_t)BS * EE;

        embed_ln_kernel<<<BS, 256, 0, stream>>>(src, emb, nin_s, nin_b, x);
        for (int l = 0; l < LL; l++) {
            ln_kernel<float><<<BS, 256, 0, stream>>>(x, ln1_s + l * EE, ln1_b + l * EE, h);
            gemm_nt<0><<<dim3(3 * EE / 64, BS / 64), 256, 0, stream>>>(
                h, inW + (size_t)l * 3 * EE * EE, inB + (size_t)l * 3 * EE, qkvf, nullptr,
                BS, 3 * EE, EE);
            attn_kernel<float><<<BB * HH * SS, 256, 0, stream>>>(qkvf, rel, o);
            gemm_nt<2><<<dim3(EE / 64, BS / 64), 256, 0, stream>>>(
                o, outW + (size_t)l * EE * EE, outB + (size_t)l * EE, x, x,
                BS, EE, EE);
            ln_kernel<float><<<BS, 256, 0, stream>>>(x, ln2_s + l * EE, ln2_b + l * EE, h);
            gemm_nt<1><<<dim3(FFD / 64, BS / 64), 256, 0, stream>>>(
                h, w1 + (size_t)l * FFD * EE, b1 + (size_t)l * FFD, ffmid, nullptr,
                BS, FFD, EE);
            gemm_nt<2><<<dim3(EE / 64, BS / 64), 256, 0, stream>>>(
                ffmid, w2 + (size_t)l * EE * FFD, b2 + (size_t)l * EE, x, x,
                BS, EE, FFD);
        }
        ln_kernel<float><<<BS, 256, 0, stream>>>(x, normf_s, normf_b, h);
        gemm_nt<0><<<dim3(VV / 64, BS / 64), 256, 0, stream>>>(
            h, dec_w, dec_b, out, nullptr, BS, VV, EE);
    }
}

// Round 3
// 674.059 us; speedup vs baseline: 4.4375x; 2.0834x over previous
//
#include <hip/hip_runtime.h>
#include <hip/hip_bf16.h>
#include <math.h>

// Problem constants
#define BB 4
#define SS 256
#define EE 512
#define HH 8
#define HD 64
#define FFD 2048
#define LL 4
#define VV 32000
#define BS (BB*SS)          // 1024 tokens
#define SQRT_E 22.627416997969522f
#define ATTN_SCALE 0.125f   // 1/sqrt(64)

typedef __bf16 bf16;
typedef __attribute__((ext_vector_type(4))) __bf16 bf16x4;
typedef __attribute__((ext_vector_type(8))) __bf16 bf16x8;
typedef __attribute__((ext_vector_type(4))) float f32x4;

#define GLOBAL_AS __attribute__((address_space(1)))
#define LDS_AS    __attribute__((address_space(3)))

__device__ __forceinline__ void load_lds16(const bf16* g, bf16* l) {
    __builtin_amdgcn_global_load_lds((const GLOBAL_AS unsigned int*)g,
                                     (LDS_AS unsigned int*)l, 16, 0, 0);
}

// ---------------- fp32 -> bf16 conversion (RNE), float4 vectorized ----------------
__global__ void cvt_bf16(const float* __restrict__ in, bf16* __restrict__ out, int n) {
    int i = (blockIdx.x * 256 + threadIdx.x) * 4;
    if (i < n) {
        float4 v = *(const float4*)(in + i);
        bf16x4 o;
        o[0] = (bf16)v.x; o[1] = (bf16)v.y; o[2] = (bf16)v.z; o[3] = (bf16)v.w;
        *(bf16x4*)(out + i) = o;
    }
}

// ---------------- LayerNorm over E=512, one block (256 thr) per row ----------------
template <typename OT>
__global__ void ln_kernel(const float* __restrict__ in, const float* __restrict__ sc,
                          const float* __restrict__ bi, OT* __restrict__ out) {
    int row = blockIdx.x;
    int t = threadIdx.x;
    const float* r = in + (size_t)row * EE;
    float v0 = r[t], v1 = r[t + 256];
    float sum = v0 + v1, sq = v0 * v0 + v1 * v1;
    #pragma unroll
    for (int off = 32; off; off >>= 1) {
        sum += __shfl_xor(sum, off);
        sq  += __shfl_xor(sq, off);
    }
    __shared__ float ssum[4], ssq[4];
    int wid = t >> 6, lane = t & 63;
    if (lane == 0) { ssum[wid] = sum; ssq[wid] = sq; }
    __syncthreads();
    sum = ssum[0] + ssum[1] + ssum[2] + ssum[3];
    sq  = ssq[0] + ssq[1] + ssq[2] + ssq[3];
    float mean = sum * (1.0f / EE);
    float var  = sq * (1.0f / EE) - mean * mean;
    float rstd = rsqrtf(var + 1e-5f);
    out[(size_t)row * EE + t]       = (OT)((v0 - mean) * rstd * sc[t] + bi[t]);
    out[(size_t)row * EE + t + 256] = (OT)((v1 - mean) * rstd * sc[t + 256] + bi[t + 256]);
}

// ---------------- Embedding gather * sqrt(E) + LayerNorm (fp32 out) ----------------
__global__ void embed_ln_kernel(const int* __restrict__ src, const float* __restrict__ emb,
                                const float* __restrict__ sc, const float* __restrict__ bi,
                                float* __restrict__ out) {
    int row = blockIdx.x;
    int t = threadIdx.x;
    const float* r = emb + (size_t)src[row] * EE;
    float v0 = r[t] * SQRT_E, v1 = r[t + 256] * SQRT_E;
    float sum = v0 + v1, sq = v0 * v0 + v1 * v1;
    #pragma unroll
    for (int off = 32; off; off >>= 1) {
        sum += __shfl_xor(sum, off);
        sq  += __shfl_xor(sq, off);
    }
    __shared__ float ssum[4], ssq[4];
    int wid = t >> 6, lane = t & 63;
    if (lane == 0) { ssum[wid] = sum; ssq[wid] = sq; }
    __syncthreads();
    sum = ssum[0] + ssum[1] + ssum[2] + ssum[3];
    sq  = ssq[0] + ssq[1] + ssq[2] + ssq[3];
    float mean = sum * (1.0f / EE);
    float var  = sq * (1.0f / EE) - mean * mean;
    float rstd = rsqrtf(var + 1e-5f);
    out[(size_t)row * EE + t]       = (v0 - mean) * rstd * sc[t] + bi[t];
    out[(size_t)row * EE + t + 256] = (v1 - mean) * rstd * sc[t + 256] + bi[t + 256];
}

// ---------------- bf16 MFMA NT GEMM: C[M,N] = A[M,K] @ W[N,K]^T ----------------
template <int BM, int BN, int MODE, int OBF16>
__global__ __launch_bounds__(256) void gemm_bf16(
        const bf16* __restrict__ A, const bf16* __restrict__ W,
        const float* __restrict__ bias, void* __restrict__ Cout,
        const float* __restrict__ res, int M, int N, int K) {
    constexpr int FM = BM / 32, FN = BN / 32;
    __shared__ bf16 Atile[BM * 32];
    __shared__ bf16 Btile[BN * 32];
    int tid = threadIdx.x;
    int wid = tid >> 6, lane = tid & 63;
    int wm = (wid >> 1) * (BM / 2), wn = (wid & 1) * (BN / 2);
    int bm = blockIdx.x * BM, bn = blockIdx.y * BN;

    f32x4 acc[FM][FN];
    #pragma unroll
    for (int i = 0; i < FM; i++)
        #pragma unroll
        for (int j = 0; j < FN; j++)
            acc[i][j] = (f32x4){0.f, 0.f, 0.f, 0.f};

    int mrow = lane & 15, kq = (lane >> 4) * 8;

    for (int k0 = 0; k0 < K; k0 += 32) {
        #pragma unroll
        for (int it = 0; it < BM / 64; it++) {
            int c = it * 256 + tid;
            int row = c >> 2, kc = (c & 3) * 8;
            load_lds16(A + (size_t)(bm + row) * K + k0 + kc, Atile + c * 8);
        }
        #pragma unroll
        for (int it = 0; it < BN / 64; it++) {
            int c = it * 256 + tid;
            int row = c >> 2, kc = (c & 3) * 8;
            load_lds16(W + (size_t)(bn + row) * K + k0 + kc, Btile + c * 8);
        }
        __syncthreads();

        bf16x8 af[FM], bfv[FN];
        #pragma unroll
        for (int i = 0; i < FM; i++)
            af[i] = *(const bf16x8*)(Atile + (wm + i * 16 + mrow) * 32 + kq);
        #pragma unroll
        for (int j = 0; j < FN; j++)
            bfv[j] = *(const bf16x8*)(Btile + (wn + j * 16 + mrow) * 32 + kq);
        #pragma unroll
        for (int i = 0; i < FM; i++)
            #pragma unroll
            for (int j = 0; j < FN; j++)
                acc[i][j] = __builtin_amdgcn_mfma_f32_16x16x32_bf16(af[i], bfv[j], acc[i][j], 0, 0, 0);
        __syncthreads();
    }

    #pragma unroll
    for (int i = 0; i < FM; i++) {
        int row0 = bm + wm + i * 16 + (lane >> 4) * 4;
        #pragma unroll
        for (int j = 0; j < FN; j++) {
            int col = bn + wn + j * 16 + (lane & 15);
            float bv = bias[col];
            #pragma unroll
            for (int r = 0; r < 4; r++) {
                int row = row0 + r;
                float v = acc[i][j][r] + bv;
                if (MODE == 1) v = 0.5f * v * (1.0f + erff(v * 0.7071067811865476f));
                if (MODE == 2) v += res[(size_t)row * N + col];
                if (OBF16) ((bf16*)Cout)[(size_t)row * N + col] = (bf16)v;
                else       ((float*)Cout)[(size_t)row * N + col] = v;
            }
        }
    }
}

// ---------------- V transpose: vT[bh][n][k] = qkv[b*256+k][1024 + h*64 + n] ----------------
__global__ __launch_bounds__(256) void transpose_v(const bf16* __restrict__ qkv,
                                                   bf16* __restrict__ vT) {
    int bh = blockIdx.x, kc = blockIdx.y;
    int b = bh >> 3, h = bh & 7;
    __shared__ __align__(16) bf16 tile[64 * 72];
    int t = threadIdx.x;
    #pragma unroll
    for (int it = 0; it < 2; it++) {
        int c = it * 256 + t; int r = c >> 3, ch = c & 7;
        bf16x8 v = *(const bf16x8*)(qkv + (size_t)(b * 256 + kc * 64 + r) * 1536 + 1024 + h * 64 + ch * 8);
        *(bf16x8*)(tile + r * 72 + ch * 8) = v;
    }
    __syncthreads();
    #pragma unroll
    for (int it = 0; it < 2; it++) {
        int c = it * 256 + t; int n = c >> 3, kch = c & 7;
        bf16x8 o;
        #pragma unroll
        for (int j = 0; j < 8; j++) o[j] = tile[(kch * 8 + j) * 72 + n];
        *(bf16x8*)(vT + ((size_t)(bh * 64 + n)) * 256 + kc * 64 + kch * 8) = o;
    }
}

// ---------------- Fused MFMA attention ----------------
// Block = (b, h, qtile of 64 queries). 256 thr = 4 waves; wave w owns query rows w*16..+16.
// scores[l,m] = 0.125*q.k + q.rel[m-l+255] + (m>l ? 1.0 : 0.0); softmax over m; O = P@V / rowsum.
__global__ __launch_bounds__(256) void attn_mfma(const bf16* __restrict__ qkv,
        const bf16* __restrict__ relb, const bf16* __restrict__ vT,
        bf16* __restrict__ o) {
    int blk = blockIdx.x;
    int qt = blk & 3, bh = blk >> 2;
    int h = bh & 7, b = bh >> 3;
    int q0 = qt * 64, j0 = 192 - q0;
    int tid = threadIdx.x;
    int wid = tid >> 6, lane = tid & 63;
    int l15 = lane & 15, quad = lane >> 4;
    int mr0 = wid * 16;

    __shared__ __align__(16) bf16 Qs[64 * 72];
    __shared__ __align__(16) bf16 Stg[64 * 72];
    __shared__ __align__(16) bf16 BP[64 * 264];   // B1s (stride 256) then P (stride 264)

    // ---- stage Q tile (64 rows x 64 dims) ----
    const size_t qbase = (size_t)(b * 256 + q0) * 1536 + h * 64;
    #pragma unroll
    for (int it = 0; it < 2; it++) {
        int c = it * 256 + tid; int r = c >> 3, ch = c & 7;
        bf16x8 v = *(const bf16x8*)(qkv + qbase + (size_t)r * 1536 + ch * 8);
        *(bf16x8*)(Qs + r * 72 + ch * 8) = v;
    }
    __syncthreads();
    bf16x8 af0 = *(const bf16x8*)(Qs + (mr0 + l15) * 72 + quad * 8);
    bf16x8 af1 = *(const bf16x8*)(Qs + (mr0 + l15) * 72 + 32 + quad * 8);

    // ---- Phase B1: bias GEMM over 320-wide rel window, row-shifted into B1s ----
    for (int jc = 0; jc < 5; jc++) {
        __syncthreads();
        const size_t rbase = (size_t)(j0 + jc * 64) * 512 + h * 64;
        #pragma unroll
        for (int it = 0; it < 2; it++) {
            int c = it * 256 + tid; int r = c >> 3, ch = c & 7;
            bf16x8 v = *(const bf16x8*)(relb + rbase + (size_t)r * 512 + ch * 8);
            *(bf16x8*)(Stg + r * 72 + ch * 8) = v;
        }
        __syncthreads();
        #pragma unroll
        for (int jt = 0; jt < 4; jt++) {
            f32x4 acc = (f32x4){0.f, 0.f, 0.f, 0.f};
            bf16x8 bv0 = *(const bf16x8*)(Stg + (jt * 16 + l15) * 72 + quad * 8);
            bf16x8 bv1 = *(const bf16x8*)(Stg + (jt * 16 + l15) * 72 + 32 + quad * 8);
            acc = __builtin_amdgcn_mfma_f32_16x16x32_bf16(af0, bv0, acc, 0, 0, 0);
            acc = __builtin_amdgcn_mfma_f32_16x16x32_bf16(af1, bv1, acc, 0, 0, 0);
            int jp = jc * 64 + jt * 16 + l15;      // col within 320-window
            #pragma unroll
            for (int r = 0; r < 4; r++) {
                int ll = mr0 + quad * 4 + r;       // local query row
                int m = jp + ll - 63;              // key index this bias lands on
                if (m >= 0 && m < 256) BP[ll * 256 + m] = (bf16)acc[r];
            }
        }
    }

    // ---- Phase S1: Q @ K^T, 4 chunks of 64 keys ----
    f32x4 S[16];
    #pragma unroll
    for (int i = 0; i < 16; i++) S[i] = (f32x4){0.f, 0.f, 0.f, 0.f};
    for (int kc = 0; kc < 4; kc++) {
        __syncthreads();
        const size_t kbase = (size_t)(b * 256 + kc * 64) * 1536 + 512 + h * 64;
        #pragma unroll
        for (int it = 0; it < 2; it++) {
            int c = it * 256 + tid; int r = c >> 3, ch = c & 7;
            bf16x8 v = *(const bf16x8*)(qkv + kbase + (size_t)r * 1536 + ch * 8);
            *(bf16x8*)(Stg + r * 72 + ch * 8) = v;
        }
        __syncthreads();
        #pragma unroll
        for (int nt = 0; nt < 4; nt++) {
            bf16x8 bv0 = *(const bf16x8*)(Stg + (nt * 16 + l15) * 72 + quad * 8);
            bf16x8 bv1 = *(const bf16x8*)(Stg + (nt * 16 + l15) * 72 + 32 + quad * 8);
            S[kc * 4 + nt] = __builtin_amdgcn_mfma_f32_16x16x32_bf16(af0, bv0, S[kc * 4 + nt], 0, 0, 0);
            S[kc * 4 + nt] = __builtin_amdgcn_mfma_f32_16x16x32_bf16(af1, bv1, S[kc * 4 + nt], 0, 0, 0);
        }
    }

    // ---- softmax (in regs; rows live in 16-lane quad groups) ----
    float rmax[4] = {-1e30f, -1e30f, -1e30f, -1e30f};
    #pragma unroll
    for (int T = 0; T < 16; T++) {
        int m = T * 16 + l15;
        #pragma unroll
        for (int r = 0; r < 4; r++) {
            int ll = mr0 + quad * 4 + r;
            float v = S[T][r] * ATTN_SCALE + (float)BP[ll * 256 + m]
                      + ((m > q0 + ll) ? 1.0f : 0.0f);
            S[T][r] = v;
            rmax[r] = fmaxf(rmax[r], v);
        }
    }
    #pragma unroll
    for (int r = 0; r < 4; r++)
        #pragma unroll
        for (int d = 1; d < 16; d <<= 1)
            rmax[r] = fmaxf(rmax[r], __shfl_xor(rmax[r], d));
    float rsum[4] = {0.f, 0.f, 0.f, 0.f};
    #pragma unroll
    for (int T = 0; T < 16; T++)
        #pragma unroll
        for (int r = 0; r < 4; r++) {
            float p = expf(S[T][r] - rmax[r]);
            S[T][r] = p;
            rsum[r] += p;
        }
    #pragma unroll
    for (int r = 0; r < 4; r++)
        #pragma unroll
        for (int d = 1; d < 16; d <<= 1)
            rsum[r] += __shfl_xor(rsum[r], d);

    __syncthreads();   // all B1s reads complete before P overwrites region
    #pragma unroll
    for (int T = 0; T < 16; T++)
        #pragma unroll
        for (int r = 0; r < 4; r++)
            BP[(mr0 + quad * 4 + r) * 264 + T * 16 + l15] = (bf16)S[T][r];

    // ---- Phase PV: O = P @ V, 4 chunks of 64 keys (V^T staged) ----
    f32x4 oacc[4];
    #pragma unroll
    for (int i = 0; i < 4; i++) oacc[i] = (f32x4){0.f, 0.f, 0.f, 0.f};
    for (int kc = 0; kc < 4; kc++) {
        __syncthreads();
        const size_t vb = (size_t)(bh * 64) * 256 + kc * 64;
        #pragma unroll
        for (int it = 0; it < 2; it++) {
            int c = it * 256 + tid; int r = c >> 3, ch = c & 7;
            bf16x8 v = *(const bf16x8*)(vT + vb + (size_t)r * 256 + ch * 8);
            *(bf16x8*)(Stg + r * 72 + ch * 8) = v;
        }
        __syncthreads();
        #pragma unroll
        for (int ks = 0; ks < 2; ks++) {
            bf16x8 ap = *(const bf16x8*)(BP + (mr0 + l15) * 264 + kc * 64 + ks * 32 + quad * 8);
            #pragma unroll
            for (int nt = 0; nt < 4; nt++) {
                bf16x8 bv = *(const bf16x8*)(Stg + (nt * 16 + l15) * 72 + ks * 32 + quad * 8);
                oacc[nt] = __builtin_amdgcn_mfma_f32_16x16x32_bf16(ap, bv, oacc[nt], 0, 0, 0);
            }
        }
    }

    #pragma unroll
    for (int nt = 0; nt < 4; nt++)
        #pragma unroll
        for (int r = 0; r < 4; r++) {
            int ll = mr0 + quad * 4 + r;
            o[(size_t)(b * 256 + q0 + ll) * 512 + h * 64 + nt * 16 + l15] =
                (bf16)(oacc[nt][r] * (1.0f / rsum[r]));
        }
}

// ---------------- fp32 fallback GEMM + attention (round-1 path) ----------------
template <int MODE>
__global__ void gemm_nt(const float* __restrict__ A, const float* __restrict__ W,
                        const float* __restrict__ bias, float* __restrict__ C,
                        const float* __restrict__ res, int M, int N, int K) {
    __shared__ float As[64][17];
    __shared__ float Ws[64][17];
    int tid = threadIdx.x;
    int tx = tid & 15, ty = tid >> 4;
    int bm = blockIdx.y * 64, bn = blockIdx.x * 64;
    float acc[4][4] = {};
    for (int k0 = 0; k0 < K; k0 += 16) {
        #pragma unroll
        for (int i = 0; i < 4; i++) {
            int idx = tid + i * 256;
            int r = idx >> 4, c = idx & 15;
            As[r][c] = A[(size_t)(bm + r) * K + k0 + c];
            Ws[r][c] = W[(size_t)(bn + r) * K + k0 + c];
        }
        __syncthreads();
        #pragma unroll
        for (int kk = 0; kk < 16; kk++) {
            float a[4], w[4];
            #pragma unroll
            for (int i = 0; i < 4; i++) a[i] = As[ty * 4 + i][kk];
            #pragma unroll
            for (int j = 0; j < 4; j++) w[j] = Ws[tx * 4 + j][kk];
            #pragma unroll
            for (int i = 0; i < 4; i++)
                #pragma unroll
                for (int j = 0; j < 4; j++)
                    acc[i][j] += a[i] * w[j];
        }
        __syncthreads();
    }
    #pragma unroll
    for (int i = 0; i < 4; i++) {
        int row = bm + ty * 4 + i;
        #pragma unroll
        for (int j = 0; j < 4; j++) {
            int col = bn + tx * 4 + j;
            float v = acc[i][j] + bias[col];
            if (MODE == 1) v = 0.5f * v * (1.0f + erff(v * 0.7071067811865476f));
            if (MODE == 2) v += res[(size_t)row * N + col];
            C[(size_t)row * N + col] = v;
        }
    }
}

__global__ void attn_kernel(const float* __restrict__ qkv, const float* __restrict__ rel_table,
                            float* __restrict__ o) {
    int blk = blockIdx.x;
    int l = blk & (SS - 1);
    int bh = blk >> 8;
    int h = bh & (HH - 1);
    int b = bh >> 3;
    int t = threadIdx.x;
    int wid = t >> 6, lane = t & 63;

    __shared__ float qs[HD];
    __shared__ float attn_s[SS];
    __shared__ float swave[4];
    __shared__ float opart[4][HD];

    const float* qrow = qkv + (size_t)(b * SS + l) * (3 * EE) + h * HD;
    if (t < HD) qs[t] = qrow[t];
    __syncthreads();

    const float* krow   = qkv + (size_t)(b * SS + t) * (3 * EE) + EE + h * HD;
    const float* relrow = rel_table + (size_t)(t - l + SS - 1) * EE + h * HD;
    const float4* k4 = reinterpret_cast<const float4*>(krow);
    const float4* r4 = reinterpret_cast<const float4*>(relrow);
    float s1 = 0.f, s2 = 0.f;
    #pragma unroll
    for (int d4 = 0; d4 < HD / 4; d4++) {
        float4 kv = k4[d4], rv = r4[d4];
        float q0 = qs[4 * d4], q1 = qs[4 * d4 + 1], q2 = qs[4 * d4 + 2], q3 = qs[4 * d4 + 3];
        s1 += q0 * kv.x + q1 * kv.y + q2 * kv.z + q3 * kv.w;
        s2 += q0 * rv.x + q1 * rv.y + q2 * rv.z + q3 * rv.w;
    }
    float val = s1 * ATTN_SCALE + s2 + ((t > l) ? 1.0f : 0.0f);

    float m = val;
    #pragma unroll
    for (int off = 32; off; off >>= 1) m = fmaxf(m, __shfl_xor(m, off));
    if (lane == 0) swave[wid] = m;
    __syncthreads();
    m = fmaxf(fmaxf(swave[0], swave[1]), fmaxf(swave[2], swave[3]));
    float p = expf(val - m);
    float s = p;
    #pragma unroll
    for (int off = 32; off; off >>= 1) s += __shfl_xor(s, off);
    __syncthreads();
    if (lane == 0) swave[wid] = s;
    __syncthreads();
    float tot = swave[0] + swave[1] + swave[2] + swave[3];
    attn_s[t] = p;
    __syncthreads();

    int d = t & 63, part = t >> 6;
    const float* vbase = qkv + (size_t)(b * SS) * (3 * EE) + 2 * EE + h * HD + d;
    float acc = 0.f;
    int m0 = part * 64;
    #pragma unroll 8
    for (int mm = m0; mm < m0 + 64; mm++)
        acc += attn_s[mm] * vbase[(size_t)mm * (3 * EE)];
    opart[part][d] = acc;
    __syncthreads();
    if (t < 64) {
        float ov = (opart[0][d] + opart[1][d] + opart[2][d] + opart[3][d]) / tot;
        o[(size_t)(b * SS + l) * EE + h * HD + d] = ov;
    }
}

extern "C" void kernel_launch(void* const* d_in, const int* in_sizes, int n_in,
                              void* d_out, int out_size, void* d_ws, size_t ws_size,
                              hipStream_t stream) {
    const int*   src    = (const int*)  d_in[0];
    const float* emb    = (const float*)d_in[1];
    const float* rel    = (const float*)d_in[2];
    const float* nin_s  = (const float*)d_in[3];
    const float* nin_b  = (const float*)d_in[4];
    const float* inW    = (const float*)d_in[5];
    const float* inB    = (const float*)d_in[6];
    const float* outW   = (const float*)d_in[7];
    const float* outB   = (const float*)d_in[8];
    const float* ln1_s  = (const float*)d_in[9];
    const float* ln1_b  = (const float*)d_in[10];
    const float* ln2_s  = (const float*)d_in[11];
    const float* ln2_b  = (const float*)d_in[12];
    const float* w1     = (const float*)d_in[13];
    const float* b1     = (const float*)d_in[14];
    const float* w2     = (const float*)d_in[15];
    const float* b2     = (const float*)d_in[16];
    const float* normf_s= (const float*)d_in[17];
    const float* normf_b= (const float*)d_in[18];
    const float* dec_w  = (const float*)d_in[19];
    const float* dec_b  = (const float*)d_in[20];
    float* out = (float*)d_out;   // [1024, 32000]

    const size_t n_inW  = (size_t)LL * 3 * EE * EE;
    const size_t n_outW = (size_t)LL * EE * EE;
    const size_t n_w1   = (size_t)LL * FFD * EE;
    const size_t n_w2   = (size_t)LL * EE * FFD;
    const size_t n_dec  = (size_t)VV * EE;
    const size_t n_rel  = (size_t)511 * EE;       // rel rows 0..510 used

    float* x    = (float*)d_ws;                       // [BS,EE] fp32 residual
    bf16*  qkvb = (bf16*)(x + (size_t)BS * EE);       // [BS,3EE] bf16
    bf16*  hb   = qkvb + (size_t)BS * 3 * EE;         // [BS,EE]
    bf16*  ob   = hb + (size_t)BS * EE;               // [BS,EE]
    bf16*  ffb  = ob + (size_t)BS * EE;               // [BS,FFD]
    bf16*  vTb  = ffb + (size_t)BS * FFD;             // [32][64][256]
    bf16*  relb = vTb + (size_t)BS * 512;             // [512][512] (row 511 unused)
    bf16*  inWb  = relb + (size_t)512 * EE;
    bf16*  outWb = inWb + n_inW;
    bf16*  w1b   = outWb + n_outW;
    bf16*  w2b   = w1b + n_w1;
    bf16*  decWb = w2b + n_w2;
    size_t needed = (size_t)((char*)(decWb + n_dec) - (char*)d_ws);

    if (ws_size >= needed) {
        cvt_bf16<<<(int)(n_inW  / 1024), 256, 0, stream>>>(inW,   inWb,  (int)n_inW);
        cvt_bf16<<<(int)(n_outW / 1024), 256, 0, stream>>>(outW,  outWb, (int)n_outW);
        cvt_bf16<<<(int)(n_w1   / 1024), 256, 0, stream>>>(w1,    w1b,   (int)n_w1);
        cvt_bf16<<<(int)(n_w2   / 1024), 256, 0, stream>>>(w2,    w2b,   (int)n_w2);
        cvt_bf16<<<(int)(n_dec  / 1024), 256, 0, stream>>>(dec_w, decWb, (int)n_dec);
        cvt_bf16<<<(int)((n_rel + 1023) / 1024), 256, 0, stream>>>(rel, relb, (int)n_rel);

        embed_ln_kernel<<<BS, 256, 0, stream>>>(src, emb, nin_s, nin_b, x);

        for (int l = 0; l < LL; l++) {
            ln_kernel<bf16><<<BS, 256, 0, stream>>>(x, ln1_s + l * EE, ln1_b + l * EE, hb);
            gemm_bf16<64, 64, 0, 1><<<dim3(BS / 64, 3 * EE / 64), 256, 0, stream>>>(
                hb, inWb + (size_t)l * 3 * EE * EE, inB + (size_t)l * 3 * EE, qkvb, nullptr,
                BS, 3 * EE, EE);
            transpose_v<<<dim3(BB * HH, 4), 256, 0, stream>>>(qkvb, vTb);
            attn_mfma<<<BB * HH * 4, 256, 0, stream>>>(qkvb, relb, vTb, ob);
            gemm_bf16<64, 64, 2, 0><<<dim3(BS / 64, EE / 64), 256, 0, stream>>>(
                ob, outWb + (size_t)l * EE * EE, outB + (size_t)l * EE, x, x,
                BS, EE, EE);
            ln_kernel<bf16><<<BS, 256, 0, stream>>>(x, ln2_s + l * EE, ln2_b + l * EE, hb);
            gemm_bf16<64, 64, 1, 1><<<dim3(BS / 64, FFD / 64), 256, 0, stream>>>(
                hb, w1b + (size_t)l * FFD * EE, b1 + (size_t)l * FFD, ffb, nullptr,
                BS, FFD, EE);
            gemm_bf16<64, 64, 2, 0><<<dim3(BS / 64, EE / 64), 256, 0, stream>>>(
                ffb, w2b + (size_t)l * EE * FFD, b2 + (size_t)l * EE, x, x,
                BS, EE, FFD);
        }

        ln_kernel<bf16><<<BS, 256, 0, stream>>>(x, normf_s, normf_b, hb);
        gemm_bf16<128, 128, 0, 0><<<dim3(BS / 128, VV / 128), 256, 0, stream>>>(
            hb, decWb, dec_b, out, nullptr, BS, VV, EE);
    } else {
        float* h     = x + (size_t)BS * EE;
        float* qkvf  = h + (size_t)BS * EE;
        float* o     = qkvf + (size_t)BS * 3 * EE;
        float* ffmid = o + (size_t)BS * EE;

        embed_ln_kernel<<<BS, 256, 0, stream>>>(src, emb, nin_s, nin_b, x);
        for (int l = 0; l < LL; l++) {
            ln_kernel<float><<<BS, 256, 0, stream>>>(x, ln1_s + l * EE, ln1_b + l * EE, h);
            gemm_nt<0><<<dim3(3 * EE / 64, BS / 64), 256, 0, stream>>>(
                h, inW + (size_t)l * 3 * EE * EE, inB + (size_t)l * 3 * EE, qkvf, nullptr,
                BS, 3 * EE, EE);
            attn_kernel<<<BB * HH * SS, 256, 0, stream>>>(qkvf, rel, o);
            gemm_nt<2><<<dim3(EE / 64, BS / 64), 256, 0, stream>>>(
                o, outW + (size_t)l * EE * EE, outB + (size_t)l * EE, x, x,
                BS, EE, EE);
            ln_kernel<float><<<BS, 256, 0, stream>>>(x, ln2_s + l * EE, ln2_b + l * EE, h);
            gemm_nt<1><<<dim3(FFD / 64, BS / 64), 256, 0, stream>>>(
                h, w1 + (size_t)l * FFD * EE, b1 + (size_t)l * FFD, ffmid, nullptr,
                BS, FFD, EE);
            gemm_nt<2><<<dim3(EE / 64, BS / 64), 256, 0, stream>>>(
                ffmid, w2 + (size_t)l * EE * FFD, b2 + (size_t)l * EE, x, x,
                BS, EE, FFD);
        }
        ln_kernel<float><<<BS, 256, 0, stream>>>(x, normf_s, normf_b, h);
        gemm_nt<0><<<dim3(VV / 64, BS / 64), 256, 0, stream>>>(
            h, dec_w, dec_b, out, nullptr, BS, VV, EE);
    }
}